// Round 4
// baseline (839.039 us; speedup 1.0000x reference)
//
#include <hip/hip_runtime.h>

// ---------- problem constants ----------
#define T_TOK 4096
#define NROWS_MAX 10240  // 8192 routed rows + per-expert 128-alignment padding (<= 9208)
#define MAX_TILES 72     // sum ceil(c_e/128) <= 64 + 7 = 71

typedef float  fv4  __attribute__((ext_vector_type(4)));
typedef __bf16 bv4  __attribute__((ext_vector_type(4)));
typedef __bf16 bv8  __attribute__((ext_vector_type(8)));

// ---------- workspace layout (bytes) ----------
#define CTRL_OFF     0
#define ROWTOK_OFF   4096         // int[10240]
#define ROWGATE_OFF  45056        // float[10240]
#define TOPIDX_OFF   86016        // int[8192]
#define TOPVAL_OFF   118784      // float[8192]
#define G_OFF        151552       // float[4096*256]
#define XB_OFF       4345856      // bf16[4096*2048]
#define W1T_OFF      21123072     // bf16[8*2048*2048]  ([E][H][D] = B^T)
#define W2T_OFF      88231936     // bf16[8*2048*2048]  ([E][D][H] = B^T)
#define HBUF_OFF     155340800    // bf16[10240*2048]
// total ~197 MB

struct Ctrl {
    int   counts[8];
    float psum[8];
    float entsum;
    int   ntiles;
    int   off[8];
    int   tile_e[MAX_TILES];
    int   tile_r0[MAX_TILES];
};

__device__ __forceinline__ float gelu_f(float x) {
    float x3 = x * x * x;
    return 0.5f * x * (1.0f + tanhf(0.7978845608028654f * (x + 0.044715f * x3)));
}

__device__ __forceinline__ void g2l16(const void* gptr, void* lptr) {
    __builtin_amdgcn_global_load_lds(
        (const __attribute__((address_space(1))) void*)gptr,
        (__attribute__((address_space(3))) void*)lptr, 16, 0, 0);
}

// ---------- K0a: w1/w2 fp32 -> bf16, transposed per expert ----------
__global__ __launch_bounds__(256) void transpose_cvt(
    const float* __restrict__ w1, const float* __restrict__ w2,
    __bf16* __restrict__ w1t, __bf16* __restrict__ w2t)
{
    int b    = blockIdx.x;
    int mat  = b >> 10;
    int tile = b & 1023;
    int trow = tile >> 5, tcol = tile & 31;
    const float* src = (mat < 8) ? (w1 + (size_t)mat * 4194304)
                                 : (w2 + (size_t)(mat - 8) * 4194304);
    __bf16* dst = (mat < 8) ? (w1t + (size_t)mat * 4194304)
                            : (w2t + (size_t)(mat - 8) * 4194304);
    __shared__ float tileS[64][65];
    int tid = threadIdx.x;
    int c = tid & 63, r4 = tid >> 6;
#pragma unroll
    for (int u = 0; u < 16; u++) {
        int rr = u * 4 + r4;
        tileS[rr][c] = src[(size_t)(trow * 64 + rr) * 2048 + tcol * 64 + c];
    }
    __syncthreads();
    int c4 = (tid & 15) * 4, r16 = tid >> 4;
#pragma unroll
    for (int u = 0; u < 4; u++) {
        int rr = u * 16 + r16;
        bv4 o;
        o[0] = (__bf16)tileS[c4][rr];
        o[1] = (__bf16)tileS[c4 + 1][rr];
        o[2] = (__bf16)tileS[c4 + 2][rr];
        o[3] = (__bf16)tileS[c4 + 3][rr];
        *(bv4*)&dst[(size_t)(tcol * 64 + rr) * 2048 + trow * 64 + c4] = o;
    }
}

// ---------- K0b: x fp32 -> bf16 ----------
__global__ __launch_bounds__(256) void cvt_x_kernel(const float* __restrict__ x,
                                                    __bf16* __restrict__ xb)
{
    size_t idx = ((size_t)blockIdx.x * 256 + threadIdx.x) * 4;
    fv4 v = *(const fv4*)(x + idx);
    bv4 o;
#pragma unroll
    for (int u = 0; u < 4; u++) o[u] = (__bf16)v[u];
    *(bv4*)(xb + idx) = o;
}

// ---------- K1: g = x @ wg1 (RAW, fp32, K-split-4, atomic accumulate) ----------
// gelu is applied in gate_kernel on load. g must be zeroed before launch.
// grid 512 = 32 Mtiles(128) x 4 Ntiles(64) x 4 Ksplits(512); 2 blocks/CU.
__global__ __launch_bounds__(256) void gating_gemm(const float* __restrict__ x,
                                                   const float* __restrict__ wg1,
                                                   float* __restrict__ g)
{
    __shared__ float As[16][132];
    __shared__ float Bs[16][68];
    int tid = threadIdx.x;
    int bid = blockIdx.x;
    int mb = bid & 31;
    int nb = (bid >> 5) & 3;
    int ks = bid >> 7;
    int tx = tid & 15, ty = tid >> 4;
    float acc[8][4];
#pragma unroll
    for (int u = 0; u < 8; u++)
#pragma unroll
        for (int v = 0; v < 4; v++) acc[u][v] = 0.f;

    int r  = tid >> 1, kq = (tid & 1) * 8;
    int kb = tid >> 4, n4 = (tid & 15) * 4;
    const float* gx = x + (size_t)(mb * 128 + r) * 2048 + ks * 512 + kq;
    const float* gw = wg1 + (size_t)(ks * 512 + kb) * 256 + nb * 64 + n4;

    for (int k0 = 0; k0 < 512; k0 += 16) {
        fv4 a0 = *(const fv4*)(gx + k0);
        fv4 a1 = *(const fv4*)(gx + k0 + 4);
        fv4 bv = *(const fv4*)(gw + (size_t)k0 * 256);
        __syncthreads();
#pragma unroll
        for (int u = 0; u < 4; u++) {
            As[kq + u][r]     = a0[u];
            As[kq + 4 + u][r] = a1[u];
        }
        *(fv4*)&Bs[kb][n4] = bv;
        __syncthreads();
#pragma unroll
        for (int k = 0; k < 16; k++) {
            fv4 b  = *(const fv4*)&Bs[k][tx * 4];
            fv4 a0v = *(const fv4*)&As[k][ty * 8];
            fv4 a1v = *(const fv4*)&As[k][ty * 8 + 4];
#pragma unroll
            for (int u = 0; u < 4; u++)
#pragma unroll
                for (int v = 0; v < 4; v++) {
                    acc[u][v]     += a0v[u] * b[v];
                    acc[u + 4][v] += a1v[u] * b[v];
                }
        }
    }
#pragma unroll
    for (int u = 0; u < 8; u++) {
        int row = mb * 128 + ty * 8 + ((u < 4) ? u : (u - 4) + 4);  // = ty*8+u
#pragma unroll
        for (int v = 0; v < 4; v++)
            atomicAdd(&g[(size_t)(mb * 128 + ty * 8 + u) * 256 + nb * 64 + tx * 4 + v],
                      acc[u][v]);
        (void)row;
    }
}

// ---------- K2: logits = gelu(g) @ wg2, softmax, top-2, loss partials ----------
__global__ __launch_bounds__(256) void gate_kernel(
    const float* __restrict__ g, const float* __restrict__ wg2,
    Ctrl* __restrict__ ctrl, int* __restrict__ topidx, float* __restrict__ topval)
{
    __shared__ float wg2s[256 * 9];
    __shared__ float psum_s[8];
    __shared__ float ent_s;
    __shared__ int   cnt_s[8];
    int tid = threadIdx.x;
    for (int i = tid; i < 2048; i += 256) {
        int k = i >> 3, e = i & 7;
        wg2s[k * 9 + e] = wg2[i];
    }
    if (tid < 8) { psum_s[tid] = 0.f; cnt_s[tid] = 0; }
    if (tid == 8) ent_s = 0.f;
    __syncthreads();

    int lane = tid & 63, wv = tid >> 6;
    int t = blockIdx.x * 4 + wv;
    fv4 g4 = *(const fv4*)&g[(size_t)t * 256 + lane * 4];
    float part[8];
#pragma unroll
    for (int e = 0; e < 8; e++) part[e] = 0.f;
#pragma unroll
    for (int u = 0; u < 4; u++) {
        int k = lane * 4 + u;
        float gv = gelu_f(g4[u]);          // gelu applied here (K1 stores raw sums)
#pragma unroll
        for (int e = 0; e < 8; e++) part[e] += gv * wg2s[k * 9 + e];
    }
#pragma unroll
    for (int e = 0; e < 8; e++)
        for (int off = 32; off; off >>= 1) part[e] += __shfl_xor(part[e], off);

    if (lane == 0) {
        float mx = part[0];
#pragma unroll
        for (int e = 1; e < 8; e++) mx = fmaxf(mx, part[e]);
        float p[8], Z = 0.f;
#pragma unroll
        for (int e = 0; e < 8; e++) { p[e] = expf(part[e] - mx); Z += p[e]; }
        float rz = 1.f / Z;
#pragma unroll
        for (int e = 0; e < 8; e++) p[e] *= rz;
        int i0 = 0;
#pragma unroll
        for (int e = 1; e < 8; e++) if (part[e] > part[i0]) i0 = e;
        int i1 = (i0 == 0) ? 1 : 0;
#pragma unroll
        for (int e = 0; e < 8; e++)
            if (e != i0 && part[e] > part[i1]) i1 = e;
        topidx[2 * t]     = i0;
        topidx[2 * t + 1] = i1;
        topval[2 * t]     = p[i0];
        topval[2 * t + 1] = p[i1];
        float ent = 0.f;
#pragma unroll
        for (int e = 0; e < 8; e++) ent += p[e] * logf(p[e] + 1e-9f);
#pragma unroll
        for (int e = 0; e < 8; e++) atomicAdd(&psum_s[e], p[e]);
        atomicAdd(&ent_s, ent);
        atomicAdd(&cnt_s[i0], 1);
        atomicAdd(&cnt_s[i1], 1);
    }
    __syncthreads();
    if (tid < 8)                    atomicAdd(&ctrl->psum[tid], psum_s[tid]);
    else if (tid == 8)              atomicAdd(&ctrl->entsum, ent_s);
    else if (tid >= 16 && tid < 24) atomicAdd(&ctrl->counts[tid - 16], cnt_s[tid - 16]);
}

// ---------- K4: offsets + tile map (128-granular) + scatter ----------
__global__ __launch_bounds__(256) void route_kernel(
    Ctrl* __restrict__ ctrl, const int* __restrict__ topidx,
    const float* __restrict__ topval, int* __restrict__ rowtok,
    float* __restrict__ rowgate)
{
    __shared__ int cur[8];
    __shared__ int offs_s[8];
    int tid = threadIdx.x;
    if (tid == 0) {
        int off = 0, nt = 0;
        for (int e = 0; e < 8; e++) {
            offs_s[e]    = off;
            ctrl->off[e] = off;
            int c = ctrl->counts[e];
            for (int m = 0; m < c; m += 128) {
                ctrl->tile_e[nt]  = e;
                ctrl->tile_r0[nt] = off + m;
                nt++;
            }
            off += ((c + 127) >> 7) << 7;
        }
        ctrl->ntiles = nt;
    }
    if (tid < 8) cur[tid] = 0;
    __syncthreads();
    for (int t = tid; t < T_TOK; t += 256) {
#pragma unroll
        for (int k = 0; k < 2; k++) {
            int e = topidx[2 * t + k];
            int p = atomicAdd(&cur[e], 1);
            int row = offs_s[e] + p;
            rowtok[row]  = t;
            rowgate[row] = topval[2 * t + k];
        }
    }
}

// ---------- grouped MFMA GEMM: 128x128 tile, BK=64, 32KB LDS ----------
// BK=32 (R3) left MfmaUtil at 15% -- the 2-barrier loop exposes load latency
// every 32 k. BK=64 halves barrier rounds and doubles loads in flight per
// drain; LDS 32KB keeps 4-5 blocks/CU of TLP.
// LDS [128 rows][8 chunks of 16B], row stride 128B (= full 32-bank span).
// Both-sides XOR swizzle (rule #21): content at (row p, phys chunk q) is
// logical chunk q ^ (p&7):
//   stage: linear g2l16 dest; source chunk = (tid&7) ^ ((tid>>3)&7)
//          (thread's dest row = tid>>3 within 32-row slab, slabs are
//          multiples of 32 so row&7 = (tid>>3)&7)
//   read:  logical chunk c = (lane>>4)|(ks<<2); phys = c ^ (l15&7); each
//          16-lane quadrant covers all 8 chunk slots -> 2 lanes/bank, free.
#define NBLK 1152

template <bool IS_FFN1>
__global__ __launch_bounds__(256, 4) void gemm_grouped(
    const __bf16* __restrict__ A,
    const __bf16* __restrict__ Bt,   // [E][N=2048][K=2048] (B^T)
    const Ctrl* __restrict__ ctrl,
    const int* __restrict__ rowtok,
    const float* __restrict__ rowgate,
    __bf16* __restrict__ hbuf,
    float* __restrict__ y)
{
    __shared__ __bf16 As[128 * 64];  // 16 KB
    __shared__ __bf16 Bs[128 * 64];  // 16 KB

    const int tid  = threadIdx.x;
    const int lane = tid & 63, w = tid >> 6;
    const int wm = w >> 1, wn = w & 1;        // 2x2 wave grid, 64x64 per wave
    const int l15 = lane & 15;
    const int stb = w * 512;                  // wave-uniform LDS dest (elements)
    const int srow = tid >> 3;                // staging row within 32-row slab
    const int sk8  = (((tid & 7) ^ ((tid >> 3) & 7)) << 3);  // inv-swz src chunk (elems)
    const int kc0  = (((lane >> 4)) ^ (l15 & 7)) << 3;       // swz read chunk ks=0
    const int kc1  = (((lane >> 4) | 4) ^ (l15 & 7)) << 3;   // swz read chunk ks=1

    int ntiles = ctrl->ntiles;
    int nitems = ntiles << 4;                 // x 16 col panels (nb)
    int item = (blockIdx.x & 7) * (NBLK / 8) + (blockIdx.x >> 3);  // XCD-chunked
    if (item >= nitems) return;

    int tl = item >> 4, nb = item & 15;
    int e  = ctrl->tile_e[tl];
    int r0 = ctrl->tile_r0[tl];

    // staging source pointers (k=0); 4 slabs of 32 rows each for A and B
    int rA0, rA1, rA2, rA3;
    if constexpr (IS_FFN1) {
        rA0 = rowtok[r0 + srow];
        rA1 = rowtok[r0 + 32 + srow];
        rA2 = rowtok[r0 + 64 + srow];
        rA3 = rowtok[r0 + 96 + srow];
    } else {
        rA0 = r0 + srow;
        rA1 = rA0 + 32;
        rA2 = rA0 + 64;
        rA3 = rA0 + 96;
    }
    const __bf16* pa0 = A + (size_t)rA0 * 2048 + sk8;
    const __bf16* pa1 = A + (size_t)rA1 * 2048 + sk8;
    const __bf16* pa2 = A + (size_t)rA2 * 2048 + sk8;
    const __bf16* pa3 = A + (size_t)rA3 * 2048 + sk8;
    const __bf16* pb0 = Bt + ((size_t)e * 2048 + nb * 128 + srow) * 2048 + sk8;
    const __bf16* pb1 = pb0 + (size_t)32 * 2048;
    const __bf16* pb2 = pb0 + (size_t)64 * 2048;
    const __bf16* pb3 = pb0 + (size_t)96 * 2048;

    fv4 acc[4][4];
#pragma unroll
    for (int i = 0; i < 4; i++)
#pragma unroll
        for (int j = 0; j < 4; j++) acc[i][j] = (fv4)0.0f;

    for (int k = 0; k < 2048; k += 64) {
        __syncthreads();                    // prior step's reads complete
        g2l16(pa0 + k, As + stb);           // rows 0..31
        g2l16(pa1 + k, As + 2048 + stb);    // rows 32..63
        g2l16(pa2 + k, As + 4096 + stb);    // rows 64..95
        g2l16(pa3 + k, As + 6144 + stb);    // rows 96..127
        g2l16(pb0 + k, Bs + stb);
        g2l16(pb1 + k, Bs + 2048 + stb);
        g2l16(pb2 + k, Bs + 4096 + stb);
        g2l16(pb3 + k, Bs + 6144 + stb);
        __syncthreads();                    // compiler drains vmcnt before barrier

#pragma unroll
        for (int ks = 0; ks < 2; ks++) {
            const int kc = ks ? kc1 : kc0;
            bv8 aF[4], bF[4];
#pragma unroll
            for (int i = 0; i < 4; i++)
                aF[i] = *(const bv8*)&As[(wm * 64 + i * 16 + l15) * 64 + kc];
#pragma unroll
            for (int j = 0; j < 4; j++)
                bF[j] = *(const bv8*)&Bs[(wn * 64 + j * 16 + l15) * 64 + kc];
#pragma unroll
            for (int i = 0; i < 4; i++)
#pragma unroll
                for (int j = 0; j < 4; j++)
                    acc[i][j] = __builtin_amdgcn_mfma_f32_16x16x32_bf16(
                        aF[i], bF[j], acc[i][j], 0, 0, 0);
        }
    }

    // epilogue: C/D layout col=lane&15, row=(lane>>4)*4+reg
    int colb = nb * 128 + wn * 64 + l15;
    int rb   = r0 + wm * 64 + (lane >> 4) * 4;
#pragma unroll
    for (int i = 0; i < 4; i++) {
#pragma unroll
        for (int rr = 0; rr < 4; rr++) {
            int rg = rb + i * 16 + rr;
            if constexpr (IS_FFN1) {
                float gate = rowgate[rg];
                size_t ho = (size_t)rg * 2048;
#pragma unroll
                for (int j = 0; j < 4; j++)
                    hbuf[ho + colb + j * 16] = (__bf16)(gelu_f(acc[i][j][rr]) * gate);
            } else {
                size_t yo = (size_t)rowtok[rg] * 2048;
#pragma unroll
                for (int j = 0; j < 4; j++)
                    atomicAdd(&y[yo + colb + j * 16], acc[i][j][rr]);
            }
        }
    }
}

// ---------- K5: final loss scalar ----------
__global__ __launch_bounds__(64) void loss_kernel(const Ctrl* __restrict__ ctrl,
                                                  float* __restrict__ out)
{
    if (threadIdx.x == 0) {
        float a = 0.f;
#pragma unroll
        for (int e = 0; e < 8; e++) {
            float pm = ctrl->psum[e] * (1.0f / 4096.0f);
            a += pm * logf(pm + 1e-9f);
        }
        out[0] = a - ctrl->entsum * (1.0f / 4096.0f);
    }
}

extern "C" void kernel_launch(void* const* d_in, const int* in_sizes, int n_in,
                              void* d_out, int out_size, void* d_ws, size_t ws_size,
                              hipStream_t stream)
{
    const float* x   = (const float*)d_in[0];
    const float* wg1 = (const float*)d_in[1];
    const float* wg2 = (const float*)d_in[2];
    const float* w1  = (const float*)d_in[3];
    const float* w2  = (const float*)d_in[4];
    float* out = (float*)d_out;

    char* ws = (char*)d_ws;
    Ctrl*   ctrl    = (Ctrl*)(ws + CTRL_OFF);
    int*    rowtok  = (int*)(ws + ROWTOK_OFF);
    float*  rowgate = (float*)(ws + ROWGATE_OFF);
    int*    topidx  = (int*)(ws + TOPIDX_OFF);
    float*  topval  = (float*)(ws + TOPVAL_OFF);
    float*  g       = (float*)(ws + G_OFF);
    __bf16* xb      = (__bf16*)(ws + XB_OFF);
    __bf16* w1t     = (__bf16*)(ws + W1T_OFF);
    __bf16* w2t     = (__bf16*)(ws + W2T_OFF);
    __bf16* hbuf    = (__bf16*)(ws + HBUF_OFF);

    hipMemsetAsync(ws + CTRL_OFF, 0, 4096, stream);
    hipMemsetAsync(ws + ROWTOK_OFF, 0, 81920, stream);    // rowtok + rowgate
    hipMemsetAsync(ws + G_OFF, 0, 4194304, stream);       // g (atomic-accumulated)
    hipMemsetAsync(d_out, 0, (size_t)out_size * sizeof(float), stream);

    transpose_cvt<<<16384, 256, 0, stream>>>(w1, w2, w1t, w2t);
    cvt_x_kernel<<<8192, 256, 0, stream>>>(x, xb);
    gating_gemm<<<512, 256, 0, stream>>>(x, wg1, g);
    gate_kernel<<<1024, 256, 0, stream>>>(g, wg2, ctrl, topidx, topval);
    route_kernel<<<1, 256, 0, stream>>>(ctrl, topidx, topval, rowtok, rowgate);
    gemm_grouped<true><<<NBLK, 256, 0, stream>>>(xb, w1t, ctrl, rowtok, rowgate, hbuf, nullptr);
    gemm_grouped<false><<<NBLK, 256, 0, stream>>>(hbuf, w2t, ctrl, rowtok, rowgate, nullptr, out);
    loss_kernel<<<1, 64, 0, stream>>>(ctrl, out + 8388608);
}